// Round 12
// baseline (1863.921 us; speedup 1.0000x reference)
//
#include <hip/hip_runtime.h>

#define B_   128
#define S_   256
#define EMB_ 256
#define H_   1024
#define NH3  3072

#define MG      16    // rows per subgroup
#define HS      16    // H columns per workgroup
#define THREADS 768   // 12 waves

typedef _Float16 f16;
typedef _Float16 h8 __attribute__((ext_vector_type(8)));
typedef float    f4 __attribute__((ext_vector_type(4)));
typedef unsigned long long u64;

#define AL64(pp) __hip_atomic_load((pp), __ATOMIC_RELAXED, __HIP_MEMORY_SCOPE_AGENT)
#define ALI(pp)  __hip_atomic_load((pp), __ATOMIC_RELAXED, __HIP_MEMORY_SCOPE_AGENT)

// ---------- gather + fp16 convert
__global__ void gather_kernel(const int* __restrict__ x, const float* __restrict__ emb,
                              f16* __restrict__ xe16) {
  int m = blockIdx.x, k = threadIdx.x;
  int b = m & 127, s = m >> 7;
  int row = x[b * S_ + s];
  xe16[m * EMB_ + k] = (f16)emb[row * EMB_ + k];
}

// ---------- transpose + fp16 convert
__global__ void transpose_cvt(const float* __restrict__ in, f16* __restrict__ out,
                              int K, int N) {
  __shared__ float tile[32][33];
  int n0 = blockIdx.x * 32, k0 = blockIdx.y * 32;
  int tx = threadIdx.x & 31, ty = threadIdx.x >> 5;
#pragma unroll
  for (int i = 0; i < 4; ++i)
    tile[ty + 8 * i][tx] = in[(k0 + ty + 8 * i) * N + n0 + tx];
  __syncthreads();
#pragma unroll
  for (int i = 0; i < 4; ++i)
    out[(n0 + ty + 8 * i) * K + k0 + tx] = (f16)tile[tx][ty + 8 * i];
}

// ---------- persistent GRU: pipelined pulls, wave role-split
__launch_bounds__(THREADS, 3)
__global__ void gru_kernel(const f16* __restrict__ xe16, const f16* __restrict__ Ut,
                           const f16* __restrict__ Wt, const float* __restrict__ hidden,
                           const float* __restrict__ bvec, float* __restrict__ out,
                           f16* __restrict__ h16, int* __restrict__ flags) {
  __shared__ f16   h_lds[2][MG * H_];     // A,B slabs, rows 2048B XOR-swizzled
  __shared__ f16   xe_lds[2][MG * EMB_];  // A,B xe, rows 512B XOR-swizzled
  __shared__ float recS[4][MG][68];       // K-split partials z|r|xh|rh

  const int tid = threadIdx.x;
  const int bid = blockIdx.x;
  const int p   = bid & 3;          // pair
  const int w   = bid >> 2;         // 0..63
  const int hc0 = w * HS;
  const int rowA = p * 32, rowB = p * 32 + 16;

  const int lane = tid & 63;
  const int wv   = tid >> 6;        // 0..11
  const int ksp  = wv & 3;
  const int cp   = wv >> 2;
  const int ln   = lane & 15;
  const int klo  = lane >> 4;
  const int bl   = tid >> 4;        // gates row (tid<256)
  const int jl   = tid & 15;

  int* flA = flags + p * 128;
  int* flB = flags + p * 128 + 64;

  h8 uf[8]; h8 wf[2];
  {
    const f16* u0 = Ut + (size_t)(cp * H_ + hc0 + ln) * H_ + ksp * 256 + klo * 8;
#pragma unroll
    for (int kt = 0; kt < 8; ++kt) uf[kt] = *(const h8*)(u0 + kt * 32);
    const f16* w0 = Wt + (size_t)(cp * H_ + hc0 + ln) * EMB_ + ksp * 64 + klo * 8;
    wf[0] = *(const h8*)(w0);
    wf[1] = *(const h8*)(w0 + 32);
  }
#pragma unroll
  for (int kt = 0; kt < 8; ++kt) asm volatile("" : "+v"(uf[kt]));
  asm volatile("" : "+v"(wf[0]), "+v"(wf[1]));

  float hprevA = 0.f, hprevB = 0.f, bz = 0.f, brr = 0.f, bxh = 0.f, brh = 0.f;
  size_t obaseA = 0, obaseB = 0, soffA = 0, soffB = 0;
  if (tid < 256) {
    int col = hc0 + jl;
    bz  = bvec[col] + bvec[NH3 + col];
    brr = bvec[H_ + col] + bvec[NH3 + H_ + col];
    bxh = bvec[2 * H_ + col];
    brh = bvec[NH3 + 2 * H_ + col];
    hprevA = hidden[(size_t)(rowA + bl) * H_ + col];
    hprevB = hidden[(size_t)(rowB + bl) * H_ + col];
    obaseA = ((size_t)(rowA + bl) * S_) * H_ + col;
    obaseB = ((size_t)(rowB + bl) * S_) * H_ + col;
    soffA  = (size_t)(rowA + bl) * H_ + col;
    soffB  = (size_t)(rowB + bl) * H_ + col;
  }

  // ---- prologue: stage A(0), B(0), xe(0) both
  for (int idx = tid; idx < 2 * MG * H_ / 4; idx += THREADS) {
    int grp = idx >> 12, i = idx & 4095;
    int r = i >> 8, c4 = i & 255;
    float4 hv = ((const float4*)(hidden + (size_t)(p * 32 + grp * 16 + r) * H_))[c4];
    unsigned lo = ((unsigned)__builtin_bit_cast(unsigned short, (f16)hv.y) << 16)
                |  (unsigned)__builtin_bit_cast(unsigned short, (f16)hv.x);
    unsigned hi = ((unsigned)__builtin_bit_cast(unsigned short, (f16)hv.w) << 16)
                |  (unsigned)__builtin_bit_cast(unsigned short, (f16)hv.z);
    uint2 pk = {lo, hi};
    *(uint2*)((char*)h_lds[grp] + r * 2048 + ((c4 * 8) ^ ((r & 7) << 4))) = pk;
  }
  for (int idx = tid; idx < 2 * MG * EMB_ / 8; idx += THREADS) {
    int grp = idx >> 9, i = idx & 511;
    int r = i >> 5, c = i & 31;
    uint4 v = ((const uint4*)(xe16 + (size_t)(p * 32 + grp * 16) * EMB_))[i];
    *(uint4*)((char*)xe_lds[grp] + r * 512 + ((c * 16) ^ ((r & 7) << 4))) = v;
  }
  __syncthreads();

#define MFMA_PHASE(GRP)                                                          \
  {                                                                              \
    f4 aU = {0.f,0.f,0.f,0.f}, aW = {0.f,0.f,0.f,0.f};                           \
    const char* hb = (const char*)h_lds[GRP] + ln * 2048;                        \
    const char* xb = (const char*)xe_lds[GRP] + ln * 512;                        \
    const int rm = (ln & 7) << 4;                                                \
    _Pragma("unroll")                                                            \
    for (int kt = 0; kt < 8; ++kt) {                                             \
      h8 a = *(const h8*)(hb + ((ksp * 512 + kt * 64 + klo * 16) ^ rm));         \
      aU = __builtin_amdgcn_mfma_f32_16x16x32_f16(a, uf[kt], aU, 0, 0, 0);       \
    }                                                                            \
    _Pragma("unroll")                                                            \
    for (int kt = 0; kt < 2; ++kt) {                                             \
      h8 a = *(const h8*)(xb + ((ksp * 128 + kt * 64 + klo * 16) ^ rm));         \
      aW = __builtin_amdgcn_mfma_f32_16x16x32_f16(a, wf[kt], aW, 0, 0, 0);       \
    }                                                                            \
    _Pragma("unroll")                                                            \
    for (int j = 0; j < 4; ++j) {                                                \
      int r = klo * 4 + j;                                                       \
      if (cp == 0)      recS[ksp][r][ln]      = aU[j] + aW[j];                   \
      else if (cp == 1) recS[ksp][r][16 + ln] = aU[j] + aW[j];                   \
      else { recS[ksp][r][32 + ln] = aW[j]; recS[ksp][r][48 + ln] = aU[j]; }     \
    }                                                                            \
  }

#define GATES(hprev, outv)                                                       \
  {                                                                              \
    float az = recS[0][bl][jl] + recS[1][bl][jl] + recS[2][bl][jl]               \
             + recS[3][bl][jl] + bz;                                             \
    float ar = recS[0][bl][16+jl] + recS[1][bl][16+jl] + recS[2][bl][16+jl]      \
             + recS[3][bl][16+jl] + brr;                                         \
    float xh = recS[0][bl][32+jl] + recS[1][bl][32+jl] + recS[2][bl][32+jl]      \
             + recS[3][bl][32+jl] + bxh;                                         \
    float rhu = recS[0][bl][48+jl] + recS[1][bl][48+jl] + recS[2][bl][48+jl]     \
              + recS[3][bl][48+jl] + brh;                                        \
    float z  = 1.f / (1.f + __expf(-az));                                        \
    float r  = 1.f / (1.f + __expf(-ar));                                        \
    float hh = 1.f - 2.f / (1.f + __expf(2.f * (xh + r * rhu)));                 \
    float hn = z * hprev + (1.f - z) * hh;                                       \
    hprev = hn; outv = hn;                                                       \
  }

  // pullers: tid in [256,704) = waves 4..10; 4096 u64 = 448*9 + 64
#define POLLW(FL, NEED)                                                          \
  for (;;) { int f = ALI((FL) + lane); if (__all(f >= (NEED))) break;            \
             __builtin_amdgcn_s_sleep(1); }

#define PULL_ISSUE(rowbase, buf, V)                                              \
  { const u64* src = (const u64*)(h16 + (size_t)(buf) * (B_ * H_)                \
                                  + (size_t)(rowbase) * H_);                     \
    int tp = tid - 256;                                                          \
    _Pragma("unroll")                                                            \
    for (int k = 0; k < 9; ++k) V[k] = AL64(src + tp + k * 448);                 \
    if (tp < 64) V[9] = AL64(src + 4032 + tp); }

#define PULL_LDS(GRP, V)                                                         \
  { int tp = tid - 256;                                                          \
    _Pragma("unroll")                                                            \
    for (int k = 0; k < 9; ++k) {                                                \
      int idx = tp + k * 448; int r_ = idx >> 8, c_ = idx & 255;                 \
      *(u64*)((char*)h_lds[GRP] + r_ * 2048 + ((c_ * 8) ^ ((r_ & 7) << 4))) = V[k]; } \
    if (tp < 64) { int idx = 4032 + tp; int r_ = idx >> 8, c_ = idx & 255;       \
      *(u64*)((char*)h_lds[GRP] + r_ * 2048 + ((c_ * 8) ^ ((r_ & 7) << 4))) = V[9]; } }

  // wave 11 (tid>=704): xe staging, 512 uint4 = 64*8
#define XE_STAGE11(GRP, rowbase, tt)                                             \
  { const uint4* xs = (const uint4*)(xe16 + ((size_t)(tt) * B_ + (rowbase)) * EMB_); \
    char* dst = (char*)xe_lds[GRP]; int tq = tid - 704;                          \
    _Pragma("unroll")                                                            \
    for (int i = 0; i < 8; ++i) {                                                \
      int idx = tq + i * 64; uint4 v = xs[idx];                                  \
      int r_ = idx >> 5, c_ = idx & 31;                                          \
      *(uint4*)(dst + r_ * 512 + ((c_ * 16) ^ ((r_ & 7) << 4))) = v; } }

  for (int t = 0; t < S_; ++t) {
    const int nb = (t + 1) & 1;
    u64 V[10];
    float outvA = 0.f, outvB = 0.f;

    //======== phase A: [poll+issue B(t)] MFMA-A | gates-A ∥ LDS-B ∥ xe-A ========
    if (t > 0 && tid >= 256 && tid < 704) {
      POLLW(flB, t)                 // strictly BEFORE issuing loads
      PULL_ISSUE(rowB, t & 1, V)    // RTT rides under MFMA-A
    }
    MFMA_PHASE(0)
    __syncthreads();                                   // barrier 1
    if (tid < 256) {
      GATES(hprevA, outvA)
      if (t < S_ - 1) {
        unsigned short hb16 = __builtin_bit_cast(unsigned short, (f16)outvA);
        __hip_atomic_store((unsigned short*)h16 + (size_t)nb * (B_ * H_) + soffA,
                           hb16, __ATOMIC_RELAXED, __HIP_MEMORY_SCOPE_AGENT);
      }
      asm volatile("s_waitcnt vmcnt(0)" ::: "memory"); // drains ONLY h-stores
    } else if (tid < 704) {
      if (t > 0) {
        asm volatile("s_waitcnt vmcnt(0)" ::: "memory");
        PULL_LDS(1, V)
      }
    } else {
      if (t < S_ - 1) XE_STAGE11(0, rowA, t + 1)
    }
    __syncthreads();                                   // barrier 2
    if (t < S_ - 1 && tid == 0)
      __hip_atomic_store(&flA[w], t + 1, __ATOMIC_RELAXED, __HIP_MEMORY_SCOPE_AGENT);

    //======== phase B: MFMA-B | gates-B ∥ [poll+issue A(t+1)] ∥ xe-B ========
    MFMA_PHASE(1)
    __syncthreads();                                   // barrier 3
    if (tid < 256) {
      GATES(hprevB, outvB)
      if (t < S_ - 1) {
        unsigned short hb16 = __builtin_bit_cast(unsigned short, (f16)outvB);
        __hip_atomic_store((unsigned short*)h16 + (size_t)nb * (B_ * H_) + soffB,
                           hb16, __ATOMIC_RELAXED, __HIP_MEMORY_SCOPE_AGENT);
      }
      asm volatile("s_waitcnt vmcnt(0)" ::: "memory");
    } else if (tid < 704) {
      if (t < S_ - 1) {
        POLLW(flA, t + 1)           // flA(t+1) published at barrier 2 (+visibility)
        PULL_ISSUE(rowA, nb, V)     // RTT rides under tail out-stores
      }
    } else {
      if (t < S_ - 1) XE_STAGE11(1, rowB, t + 1)
    }
    __syncthreads();                                   // barrier 4
    if (t < S_ - 1 && tid == 0)
      __hip_atomic_store(&flB[w], t + 1, __ATOMIC_RELAXED, __HIP_MEMORY_SCOPE_AGENT);

    //======== tail: out-stores ∥ LDS-A(t+1) ========
    if (tid < 256) {
      out[obaseA + (size_t)t * H_] = outvA;
      out[obaseB + (size_t)t * H_] = outvB;
      if (t == S_ - 1) {
        out[(size_t)B_ * S_ * H_ + soffA] = outvA;
        out[(size_t)B_ * S_ * H_ + soffB] = outvB;
      }
    } else if (tid < 704) {
      if (t < S_ - 1) {
        asm volatile("s_waitcnt vmcnt(0)" ::: "memory");
        PULL_LDS(0, V)
      }
    }
    __syncthreads();                                   // barrier 5
    // Overwrite-safety (double buffer, pipelined): WG writes B(t+1) after passing
    // phase-A poll flB>=t; flB_C = t certifies C completed gates-B(t-1), which is
    // after C's phase-A vmcnt'd pull of B(t-1) -> no consumer still reads the
    // buffer being overwritten. Symmetric for A via poll flA>=t at prior phase-B.
  }
}

extern "C" void kernel_launch(void* const* d_in, const int* in_sizes, int n_in,
                              void* d_out, int out_size, void* d_ws, size_t ws_size,
                              hipStream_t stream) {
  const int*   x      = (const int*)  d_in[0];
  const float* hidden = (const float*)d_in[1];
  const float* emb    = (const float*)d_in[2];
  const float* W      = (const float*)d_in[3];
  const float* U      = (const float*)d_in[4];
  const float* bvec   = (const float*)d_in[5];
  float* out = (float*)d_out;

  char* ws = (char*)d_ws;
  f16* Ut    = (f16*)(ws);                   //  6,291,456 B
  f16* Wt    = (f16*)(ws + 6291456);         //  1,572,864 B
  f16* xe16  = (f16*)(ws + 7864320);         // 16,777,216 B
  f16* h16   = (f16*)(ws + 24641536);        //    524,288 B (double buffer)
  int* flags = (int*)(ws + 25165824);        //  4*128*4 = 2048 B

  hipMemsetAsync(flags, 0, 2048, stream);
  hipLaunchKernelGGL(transpose_cvt, dim3(NH3 / 32, H_ / 32), dim3(256), 0, stream,
                     U, Ut, H_, NH3);
  hipLaunchKernelGGL(transpose_cvt, dim3(NH3 / 32, EMB_ / 32), dim3(256), 0, stream,
                     W, Wt, EMB_, NH3);
  hipLaunchKernelGGL(gather_kernel, dim3(B_ * S_), dim3(EMB_), 0, stream, x, emb, xe16);

  void* args[] = { (void*)&xe16, (void*)&Ut, (void*)&Wt, (void*)&hidden,
                   (void*)&bvec, (void*)&out, (void*)&h16, (void*)&flags };
  hipLaunchCooperativeKernel(reinterpret_cast<void*>(gru_kernel),
                             dim3(256), dim3(THREADS), args, 0, stream);
}

// Round 13
// 1063.974 us; speedup vs baseline: 1.7518x; 1.7518x over previous
//
#include <hip/hip_runtime.h>

#define B_   128
#define S_   256
#define EMB_ 256
#define H_   1024
#define NH3  3072

#define G_      8     // batch groups
#define NW      32    // workgroups per group
#define MG      16    // batch rows per group
#define HS      32    // H columns per workgroup
#define THREADS 768   // 12 waves

typedef _Float16 f16;
typedef _Float16 h8 __attribute__((ext_vector_type(8)));
typedef float    f4 __attribute__((ext_vector_type(4)));
typedef unsigned long long u64;

#define AL64(pp) __hip_atomic_load((pp), __ATOMIC_RELAXED, __HIP_MEMORY_SCOPE_AGENT)
#define ALI(pp)  __hip_atomic_load((pp), __ATOMIC_RELAXED, __HIP_MEMORY_SCOPE_AGENT)

// ---------- gather + fp16 convert
__global__ void gather_kernel(const int* __restrict__ x, const float* __restrict__ emb,
                              f16* __restrict__ xe16) {
  int m = blockIdx.x, k = threadIdx.x;
  int b = m & 127, s = m >> 7;
  int row = x[b * S_ + s];
  xe16[m * EMB_ + k] = (f16)emb[row * EMB_ + k];
}

// ---------- transpose + fp16 convert: out[n*K + k] = (f16) in[k*N + n]
__global__ void transpose_cvt(const float* __restrict__ in, f16* __restrict__ out,
                              int K, int N) {
  __shared__ float tile[32][33];
  int n0 = blockIdx.x * 32, k0 = blockIdx.y * 32;
  int tx = threadIdx.x & 31, ty = threadIdx.x >> 5;
#pragma unroll
  for (int i = 0; i < 4; ++i)
    tile[ty + 8 * i][tx] = in[(k0 + ty + 8 * i) * N + n0 + tx];
  __syncthreads();
#pragma unroll
  for (int i = 0; i < 4; ++i)
    out[(n0 + ty + 8 * i) * K + k0 + tx] = (f16)tile[tx][ty + 8 * i];
}

// ---------- persistent GRU (r7 protocol, per-wave incremental pull)
__launch_bounds__(THREADS, 3)
__global__ void gru_kernel(const f16* __restrict__ xe16, const f16* __restrict__ Ut,
                           const f16* __restrict__ Wt, const float* __restrict__ hidden,
                           const float* __restrict__ bvec, float* __restrict__ out,
                           f16* __restrict__ h16, int* __restrict__ flags) {
  __shared__ f16   h_lds[MG * H_];        // 32 KB, rows of 2048B, XOR-swizzled
  __shared__ f16   xe_lds[2][MG * EMB_];  // 16 KB, rows of 512B, XOR-swizzled
  __shared__ float recS[4][MG][100];      // K-split partials: z|r|xh
  __shared__ float recU[4][MG][36];       // K-split partials: rh

  const int tid = threadIdx.x;
  const int bid = blockIdx.x;
  const int g   = bid & 7;
  const int w   = bid >> 3;         // 0..31
  const int gb0 = g * MG;
  const int hc0 = w * HS;

  const int lane = tid & 63;
  const int wv   = tid >> 6;        // 0..11
  const int ksp  = wv & 3;          // K quarter
  const int cp   = wv >> 2;         // gate 0=z 1=r 2=hh
  const int ln   = lane & 15;
  const int klo  = lane >> 4;
  const int bl   = tid >> 5;        // gate row (tid<512)
  const int jl   = tid & 31;

  int* gflags = flags + g * NW;

  // ---- weights register-resident (r7 layout)
  h8 uf0[8], uf1[8], wf0[2], wf1[2];
  {
    const f16* u0 = Ut + (size_t)(cp * H_ + hc0 + ln) * H_ + ksp * 256 + klo * 8;
    const f16* u1 = u0 + (size_t)16 * H_;
#pragma unroll
    for (int kt = 0; kt < 8; ++kt) { uf0[kt] = *(const h8*)(u0 + kt * 32);
                                     uf1[kt] = *(const h8*)(u1 + kt * 32); }
    const f16* w0 = Wt + (size_t)(cp * H_ + hc0 + ln) * EMB_ + ksp * 64 + klo * 8;
    const f16* w1 = w0 + 16 * EMB_;
#pragma unroll
    for (int kt = 0; kt < 2; ++kt) { wf0[kt] = *(const h8*)(w0 + kt * 32);
                                     wf1[kt] = *(const h8*)(w1 + kt * 32); }
  }
#pragma unroll
  for (int kt = 0; kt < 8; ++kt) { asm volatile("" : "+v"(uf0[kt])); asm volatile("" : "+v"(uf1[kt])); }
  asm volatile("" : "+v"(wf0[0]), "+v"(wf0[1]), "+v"(wf1[0]), "+v"(wf1[1]));

  // ---- per-thread gate state
  float hprev = 0.f, bz = 0.f, brr = 0.f, bxh = 0.f, brh = 0.f;
  size_t obase = 0, soff = 0;
  if (tid < 512) {
    int col = hc0 + jl;
    bz  = bvec[col] + bvec[NH3 + col];
    brr = bvec[H_ + col] + bvec[NH3 + H_ + col];
    bxh = bvec[2 * H_ + col];
    brh = bvec[NH3 + 2 * H_ + col];
    hprev = hidden[(size_t)(gb0 + bl) * H_ + col];
    obase = ((size_t)(gb0 + bl) * S_) * H_ + col;
    soff  = (size_t)(gb0 + bl) * H_ + col;
  }

  // ---- prologue: h(0) from hidden (f32->f16, swizzled); xe(0)
  for (int idx = tid; idx < MG * H_ / 4; idx += THREADS) {
    int r = idx >> 8, c4 = idx & 255;
    float4 hv = ((const float4*)(hidden + (size_t)(gb0 + r) * H_))[c4];
    unsigned lo = ((unsigned)__builtin_bit_cast(unsigned short, (f16)hv.y) << 16)
                |  (unsigned)__builtin_bit_cast(unsigned short, (f16)hv.x);
    unsigned hi = ((unsigned)__builtin_bit_cast(unsigned short, (f16)hv.w) << 16)
                |  (unsigned)__builtin_bit_cast(unsigned short, (f16)hv.z);
    uint2 pk = {lo, hi};
    *(uint2*)((char*)h_lds + r * 2048 + ((c4 * 8) ^ ((r & 7) << 4))) = pk;
  }
  for (int idx = tid; idx < MG * EMB_ / 8; idx += THREADS) {
    uint4 v = ((const uint4*)(xe16 + (size_t)gb0 * EMB_))[idx];
    int r = idx >> 5, c = idx & 31;
    *(uint4*)((char*)xe_lds[0] + r * 512 + ((c * 16) ^ ((r & 7) << 4))) = v;
  }
  __syncthreads();

  // pull assignment: wave wv owns slices {wv, wv+12, wv+24(if wv<8)}
  const int s0p = wv, s1p = wv + 12, s2p = wv + 24;
  const int pr  = lane >> 2;        // slice row 0..15
  const int pc  = (lane & 3) * 2;   // u64 column base {0,2,4,6}

  for (int t = 0; t < S_; ++t) {
    // ---- MFMA: U (16) + W (4) per wave
    f4 a0 = {0.f,0.f,0.f,0.f}, a1 = {0.f,0.f,0.f,0.f};
    f4 a2 = {0.f,0.f,0.f,0.f}, a3 = {0.f,0.f,0.f,0.f};
    const char* hb = (const char*)h_lds + ln * 2048;
    const char* xb = (const char*)xe_lds[t & 1] + ln * 512;
    const int rm = (ln & 7) << 4;
#pragma unroll
    for (int kt = 0; kt < 8; ++kt) {
      h8 a = *(const h8*)(hb + ((ksp * 512 + kt * 64 + klo * 16) ^ rm));
      a0 = __builtin_amdgcn_mfma_f32_16x16x32_f16(a, uf0[kt], a0, 0, 0, 0);
      a1 = __builtin_amdgcn_mfma_f32_16x16x32_f16(a, uf1[kt], a1, 0, 0, 0);
    }
#pragma unroll
    for (int kt = 0; kt < 2; ++kt) {
      h8 a = *(const h8*)(xb + ((ksp * 128 + kt * 64 + klo * 16) ^ rm));
      a2 = __builtin_amdgcn_mfma_f32_16x16x32_f16(a, wf0[kt], a2, 0, 0, 0);
      a3 = __builtin_amdgcn_mfma_f32_16x16x32_f16(a, wf1[kt], a3, 0, 0, 0);
    }
#pragma unroll
    for (int j = 0; j < 4; ++j) {
      int r = klo * 4 + j;
      if (cp < 2) {
        recS[ksp][r][cp * 32 + ln]      = a0[j] + a2[j];
        recS[ksp][r][cp * 32 + 16 + ln] = a1[j] + a3[j];
      } else {
        recS[ksp][r][64 + ln] = a2[j];
        recS[ksp][r][80 + ln] = a3[j];
        recU[ksp][r][ln]      = a0[j];
        recU[ksp][r][16 + ln] = a1[j];
      }
    }
    __syncthreads();                                   // B1

    // ---- gates + h(t+1) publish
    float outv = 0.f;
    if (tid < 512) {
      float az = recS[0][bl][jl] + recS[1][bl][jl] + recS[2][bl][jl] + recS[3][bl][jl] + bz;
      float ar = recS[0][bl][32+jl] + recS[1][bl][32+jl] + recS[2][bl][32+jl] + recS[3][bl][32+jl] + brr;
      float xh = recS[0][bl][64+jl] + recS[1][bl][64+jl] + recS[2][bl][64+jl] + recS[3][bl][64+jl] + bxh;
      float rhu = recU[0][bl][jl] + recU[1][bl][jl] + recU[2][bl][jl] + recU[3][bl][jl] + brh;
      float z  = 1.f / (1.f + __expf(-az));
      float r  = 1.f / (1.f + __expf(-ar));
      float hh = 1.f - 2.f / (1.f + __expf(2.f * (xh + r * rhu)));
      float hn = z * hprev + (1.f - z) * hh;
      hprev = hn; outv = hn;
      if (t < S_ - 1) {
        unsigned short hb16 = __builtin_bit_cast(unsigned short, (f16)hn);
        __hip_atomic_store((unsigned short*)(h16 + (size_t)((t + 1) & 1) * (B_ * H_)) + soff,
                           hb16, __ATOMIC_RELAXED, __HIP_MEMORY_SCOPE_AGENT);
      }
    }
    if (t == S_ - 1) {
      if (tid < 512) {
        out[obase + (size_t)t * H_] = outv;
        out[(size_t)B_ * S_ * H_ + soff] = outv;
      }
      break;
    }

    asm volatile("s_waitcnt vmcnt(0)" ::: "memory");   // drain h-stores
    __syncthreads();                                   // B2
    if (tid == 0)
      __hip_atomic_store(&gflags[w], t + 1, __ATOMIC_RELAXED, __HIP_MEMORY_SCOPE_AGENT);

    // ---- visibility window: out stores / xe staging (independent work first)
    if (tid < 512) {
      out[obase + (size_t)t * H_] = outv;
    } else {
      const uint4* src = (const uint4*)(xe16 + ((size_t)(t + 1) * B_ + gb0) * EMB_);
      char* dst = (char*)xe_lds[(t + 1) & 1];
#pragma unroll
      for (int i = 0; i < 2; ++i) {
        int idx = (tid - 512) * 2 + i;
        uint4 v = src[idx];
        int r = idx >> 5, c = idx & 31;
        *(uint4*)(dst + r * 512 + ((c * 16) ^ ((r & 7) << 4))) = v;
      }
    }

    // ---- per-wave incremental pull of h(t+1): poll own flags, pull own slices
    {
      const int need = t + 1;
      const u64* hbuf = (const u64*)(h16 + (size_t)((t + 1) & 1) * (B_ * H_));
      const int rowu = (gb0 + pr) * 256;     // 256 u64 per h row
      for (;;) { int f = ALI(&gflags[s0p]); if (f >= need) break; __builtin_amdgcn_s_sleep(1); }
      for (;;) { int f = ALI(&gflags[s1p]); if (f >= need) break; __builtin_amdgcn_s_sleep(1); }
      if (wv < 8)
        for (;;) { int f = ALI(&gflags[s2p]); if (f >= need) break; __builtin_amdgcn_s_sleep(1); }
      u64 va0 = AL64(hbuf + rowu + s0p * 8 + pc);
      u64 va1 = AL64(hbuf + rowu + s0p * 8 + pc + 1);
      u64 vb0 = AL64(hbuf + rowu + s1p * 8 + pc);
      u64 vb1 = AL64(hbuf + rowu + s1p * 8 + pc + 1);
      u64 vc0 = 0, vc1 = 0;
      if (wv < 8) {
        vc0 = AL64(hbuf + rowu + s2p * 8 + pc);
        vc1 = AL64(hbuf + rowu + s2p * 8 + pc + 1);
      }
      char* hd = (char*)h_lds + pr * 2048;
      const int prm = (pr & 7) << 4;
      *(u64*)(hd + ((s0p * 64 + pc * 8    ) ^ prm)) = va0;
      *(u64*)(hd + ((s0p * 64 + pc * 8 + 8) ^ prm)) = va1;
      *(u64*)(hd + ((s1p * 64 + pc * 8    ) ^ prm)) = vb0;
      *(u64*)(hd + ((s1p * 64 + pc * 8 + 8) ^ prm)) = vb1;
      if (wv < 8) {
        *(u64*)(hd + ((s2p * 64 + pc * 8    ) ^ prm)) = vc0;
        *(u64*)(hd + ((s2p * 64 + pc * 8 + 8) ^ prm)) = vc1;
      }
    }
    __syncthreads();                                   // B3
    // Write-safety: WG stores h(t+2) into buf[t&1] only after gates(t+1), which
    // follows its own pull(t+1) where all 32 flags >= t+1 were observed; flag_C
    // = t+1 certifies C's h(t)-reads (from buf[t&1]) completed (per-wave loads
    // drained before B3 of C's step t). Same induction as r5/r7.
  }
}

extern "C" void kernel_launch(void* const* d_in, const int* in_sizes, int n_in,
                              void* d_out, int out_size, void* d_ws, size_t ws_size,
                              hipStream_t stream) {
  const int*   x      = (const int*)  d_in[0];
  const float* hidden = (const float*)d_in[1];
  const float* emb    = (const float*)d_in[2];
  const float* W      = (const float*)d_in[3];
  const float* U      = (const float*)d_in[4];
  const float* bvec   = (const float*)d_in[5];
  float* out = (float*)d_out;

  char* ws = (char*)d_ws;
  f16* Ut    = (f16*)(ws);                   //  6,291,456 B
  f16* Wt    = (f16*)(ws + 6291456);         //  1,572,864 B
  f16* xe16  = (f16*)(ws + 7864320);         // 16,777,216 B
  f16* h16   = (f16*)(ws + 24641536);        //    524,288 B (double buffer)
  int* flags = (int*)(ws + 25165824);        //  8*32*4 = 1024 B

  hipMemsetAsync(flags, 0, 1024, stream);
  hipLaunchKernelGGL(transpose_cvt, dim3(NH3 / 32, H_ / 32), dim3(256), 0, stream,
                     U, Ut, H_, NH3);
  hipLaunchKernelGGL(transpose_cvt, dim3(NH3 / 32, EMB_ / 32), dim3(256), 0, stream,
                     W, Wt, EMB_, NH3);
  hipLaunchKernelGGL(gather_kernel, dim3(B_ * S_), dim3(EMB_), 0, stream, x, emb, xe16);

  void* args[] = { (void*)&xe16, (void*)&Ut, (void*)&Wt, (void*)&hidden,
                   (void*)&bvec, (void*)&out, (void*)&h16, (void*)&flags };
  hipLaunchCooperativeKernel(reinterpret_cast<void*>(gru_kernel),
                             dim3(G_ * NW), dim3(THREADS), args, 0, stream);
}